// Round 6
// baseline (4419.878 us; speedup 1.0000x reference)
//
#include <hip/hip_runtime.h>
#include <hip/hip_bf16.h>

#define T_STEPS 512
#define INP     512
#define NB      256
#define HID     1024
#define WID     512
#define KZ      1536   // HID + INP
#define ZSZ     (NB * KZ)

typedef short          bf16x8   __attribute__((ext_vector_type(8)));
typedef float          f32x4    __attribute__((ext_vector_type(4)));
typedef float          f32x2    __attribute__((ext_vector_type(2)));
typedef unsigned short ushort8  __attribute__((ext_vector_type(8)));
typedef unsigned short ushort2v __attribute__((ext_vector_type(2)));
typedef unsigned short ushort4v __attribute__((ext_vector_type(4)));
typedef unsigned long long u64;
typedef u64            u64x2    __attribute__((ext_vector_type(2)));

__device__ __forceinline__ unsigned short f2bf(float x) {
  __hip_bfloat16 h = __float2bfloat16(x);
  return __builtin_bit_cast(unsigned short, h);
}
__device__ __forceinline__ float sigm(float x) { return 1.0f / (1.0f + __expf(-x)); }

// ---- coherence-point (LLC) resident accesses for the z ring buffer ----
// Agent-scope relaxed atomics (sc0|sc1): bypass the non-coherent L1/L2 and
// read/write the LLC directly. Round-4 proven: no cache maintenance needed.
__device__ __forceinline__ bf16x8 zld16(const unsigned short* p) {
  u64x2 v;
  v.x = __hip_atomic_load((const u64*)p,       __ATOMIC_RELAXED, __HIP_MEMORY_SCOPE_AGENT);
  v.y = __hip_atomic_load((const u64*)(p + 4), __ATOMIC_RELAXED, __HIP_MEMORY_SCOPE_AGENT);
  return __builtin_bit_cast(bf16x8, v);
}
__device__ __forceinline__ void zst4(unsigned short* p, ushort2v v) {
  __hip_atomic_store((unsigned*)p, __builtin_bit_cast(unsigned, v),
                     __ATOMIC_RELAXED, __HIP_MEMORY_SCOPE_AGENT);
}
__device__ __forceinline__ void zst8(unsigned short* p, ushort4v v) {
  __hip_atomic_store((u64*)p, __builtin_bit_cast(u64, v),
                     __ATOMIC_RELAXED, __HIP_MEMORY_SCOPE_AGENT);
}

// ---- per-role monotonic tickets (agent scope, LLC — proven mechanism) ----
// bars layout per slice (64-word line): [0]=h_arr [1]=x_arr [2]=y_arr
__device__ __forceinline__ void poll1(unsigned* p, unsigned tgt) {
  while (__hip_atomic_load(p, __ATOMIC_RELAXED, __HIP_MEMORY_SCOPE_AGENT) < tgt)
    __builtin_amdgcn_s_sleep(1);
}
__device__ __forceinline__ void poll2(u64* p, unsigned lo, unsigned hi) {
  for (;;) {
    const u64 v = __hip_atomic_load(p, __ATOMIC_RELAXED, __HIP_MEMORY_SCOPE_AGENT);
    if ((unsigned)v >= lo && (unsigned)(v >> 32) >= hi) return;
    __builtin_amdgcn_s_sleep(1);
  }
}
// All my stores visible at LLC, then bump my role counter once per WG.
__device__ __forceinline__ void arrive(unsigned* ctr) {
  asm volatile("s_waitcnt vmcnt(0)" ::: "memory");
  __syncthreads();
  if (threadIdx.x == 0)
    __hip_atomic_fetch_add(ctr, 1u, __ATOMIC_RELAXED, __HIP_MEMORY_SCOPE_AGENT);
}

// ---------------- setup: z ring init (z_0 full, x_1 part), zero tickets ----------------
__global__ void elman_setup(const float* __restrict__ h0, const float* __restrict__ xs,
                            unsigned short* __restrict__ zT, unsigned* __restrict__ bars) {
  const int b = blockIdx.x;   // batch column 0..255
  if (b == 0) {
    for (int j = threadIdx.x; j < 512; j += blockDim.x) bars[j] = 0u;
  }
  for (int k = threadIdx.x; k < KZ; k += blockDim.x) {   // buf0 = z_0
    const float v = (k < HID) ? h0[k] : xs[(size_t)(k - HID) * NB + b];
    zT[(size_t)b * KZ + k] = f2bf(v);
  }
  for (int i = threadIdx.x; i < INP; i += blockDim.x)    // buf1 x-part = x_1
    zT[(size_t)ZSZ + (size_t)b * KZ + HID + i] = f2bf(xs[(size_t)(INP + i) * NB + b]);
}

// LDS partial-sum buffer: 8 waves x [32 cols][stride 36 words]
#define PSTR 36
#define PWSZ (32 * PSTR)

// ---------------- persistent sequential kernel ----------------
// 256 WGs x 512 threads. slice = wg & 7 (32 WGs: 16 h + 8 y + 8 x), 4-deep z ring.
// Phase t:  h: z_{t+1}h <- sigm(Wh @ z_t)          needs h_arr>=16t, x_arr>=8(t-1)
//           y: out[t-1] <- sigm(Wy @ z_t.h)        needs h_arr>=16t        (t>=1)
//           x: z_{t+2}.x <- xs[t+2]                needs h_arr>=16(t-1)    (t<=T-3)
// Anti-dep for h stores into buf (t+1)&3: y_arr >= 8(t-2) (checked after MFMA).
__global__ void __launch_bounds__(512, 2) elman_seq(
    const float* __restrict__ xs,
    const float* __restrict__ Wh, const float* __restrict__ bh,
    const float* __restrict__ Wy, const float* __restrict__ by,
    unsigned short* __restrict__ zT, float* __restrict__ out,
    unsigned* __restrict__ bars) {
  __shared__ float P[8 * PWSZ];
  const int wg = blockIdx.x, tid = threadIdx.x;
  const int w = tid >> 6, lane = tid & 63;
  const int lr = lane & 15, lk = lane >> 4;
  unsigned* bar = bars + (wg & 7) * 64;   // [0]=h_arr [1]=x_arr [2]=y_arr

  if (wg < 128) {
    // ================= h role =================
    const int m0 = (wg >> 3) * 64;
    const int n0 = (wg & 7) * 32;
    const int kw = w * 192;
    bf16x8 A[4][6];                         // resident W_h fragments: 96 VGPRs
#pragma unroll
    for (int mt = 0; mt < 4; ++mt)
#pragma unroll
      for (int kc = 0; kc < 6; ++kc) {
        const float* wp = Wh + (size_t)(m0 + mt * 16 + lr) * KZ + kw + kc * 32 + lk * 8;
        const f32x4 f0 = *(const f32x4*)wp;
        const f32x4 f1 = *(const f32x4*)(wp + 4);
        ushort8 a;
#pragma unroll
        for (int e = 0; e < 4; ++e) { a[e] = f2bf(f0[e]); a[4 + e] = f2bf(f1[e]); }
        A[mt][kc] = __builtin_bit_cast(bf16x8, a);
      }
    const int lcol = tid >> 4;
    const int r2 = (tid & 15) * 2;
    f32x2 bias[2];
#pragma unroll
    for (int hf = 0; hf < 2; ++hf) bias[hf] = *(const f32x2*)&bh[m0 + hf * 32 + r2];
    float* Pw = P + w * PWSZ;

    for (int t = 0; t <= T_STEPS; ++t) {
      if (t < T_STEPS) {
        const unsigned short* zc = zT + (size_t)(t & 3) * ZSZ;
        unsigned short* zn = zT + (size_t)((t + 1) & 3) * ZSZ;
        if (t >= 1) {
          if (tid == 0) poll2((u64*)bar, 16u * (unsigned)t,
                              (t >= 2) ? 8u * (unsigned)(t - 1) : 0u);
          __syncthreads();
        }
        const unsigned short* zb = zc + (size_t)(n0 + lr) * KZ + kw + lk * 8;
        f32x4 acc[4][2];
#pragma unroll
        for (int mt = 0; mt < 4; ++mt)
#pragma unroll
          for (int nt = 0; nt < 2; ++nt) acc[mt][nt] = (f32x4){0.f, 0.f, 0.f, 0.f};
#pragma unroll
        for (int kc = 0; kc < 6; ++kc)
#pragma unroll
          for (int nt = 0; nt < 2; ++nt) {
            const bf16x8 b = zld16(zb + nt * (16 * KZ) + kc * 32);
#pragma unroll
            for (int mt = 0; mt < 4; ++mt)
              acc[mt][nt] = __builtin_amdgcn_mfma_f32_16x16x32_bf16(A[mt][kc], b, acc[mt][nt], 0, 0, 0);
          }
        // anti-dep on buf (t+1)&3: y readers of phase t-3 done (2 phases slack)
        if (t >= 3 && tid == 0) poll1(bar + 2, 8u * (unsigned)(t - 2));
        __syncthreads();
        // two-pass cross-wave K reduction through LDS
#pragma unroll
        for (int hf = 0; hf < 2; ++hf) {
#pragma unroll
          for (int mp = 0; mp < 2; ++mp) {
            const int mt = hf * 2 + mp;
#pragma unroll
            for (int nt = 0; nt < 2; ++nt)
              *(f32x4*)&Pw[(nt * 16 + lr) * PSTR + mp * 16 + lk * 4] = acc[mt][nt];
          }
          __syncthreads();
          f32x2 s = {0.f, 0.f};
#pragma unroll
          for (int ww = 0; ww < 8; ++ww)
            s += *(const f32x2*)&P[ww * PWSZ + lcol * PSTR + r2];
          s += bias[hf];
          ushort2v o2;
          o2[0] = f2bf(sigm(s[0]));
          o2[1] = f2bf(sigm(s[1]));
          zst4(zn + (size_t)(n0 + lcol) * KZ + m0 + hf * 32 + r2, o2);
          if (hf == 0) __syncthreads();
        }
      }
      arrive(bar + 0);
    }

  } else if (wg < 192) {
    // ================= y role =================
    const int idx = wg - 128;
    const int m0 = (idx >> 3) * 64;
    const int n0 = (idx & 7) * 32;
    const int kw = w * 128;
    bf16x8 A[4][4];                         // resident W_y fragments: 64 VGPRs
#pragma unroll
    for (int mt = 0; mt < 4; ++mt)
#pragma unroll
      for (int kc = 0; kc < 4; ++kc) {
        const float* wp = Wy + (size_t)(m0 + mt * 16 + lr) * HID + kw + kc * 32 + lk * 8;
        const f32x4 f0 = *(const f32x4*)wp;
        const f32x4 f1 = *(const f32x4*)(wp + 4);
        ushort8 a;
#pragma unroll
        for (int e = 0; e < 4; ++e) { a[e] = f2bf(f0[e]); a[4 + e] = f2bf(f1[e]); }
        A[mt][kc] = __builtin_bit_cast(bf16x8, a);
      }
    const int lcol = tid & 31;
    const int r2 = (tid >> 5) * 2;
    f32x2 bias[2];
#pragma unroll
    for (int hf = 0; hf < 2; ++hf) bias[hf] = *(const f32x2*)&by[m0 + hf * 32 + r2];
    float* Pw = P + w * PWSZ;

    for (int t = 0; t <= T_STEPS; ++t) {
      if (t >= 1) {
        const unsigned short* zc = zT + (size_t)(t & 3) * ZSZ;
        if (tid == 0) poll1(bar + 0, 16u * (unsigned)t);
        __syncthreads();
        const unsigned short* zb = zc + (size_t)(n0 + lr) * KZ + kw + lk * 8;
        f32x4 acc[4][2];
#pragma unroll
        for (int mt = 0; mt < 4; ++mt)
#pragma unroll
          for (int nt = 0; nt < 2; ++nt) acc[mt][nt] = (f32x4){0.f, 0.f, 0.f, 0.f};
#pragma unroll
        for (int kc = 0; kc < 4; ++kc)
#pragma unroll
          for (int nt = 0; nt < 2; ++nt) {
            const bf16x8 b = zld16(zb + nt * (16 * KZ) + kc * 32);
#pragma unroll
            for (int mt = 0; mt < 4; ++mt)
              acc[mt][nt] = __builtin_amdgcn_mfma_f32_16x16x32_bf16(A[mt][kc], b, acc[mt][nt], 0, 0, 0);
          }
        float* op = out + (size_t)(t - 1) * (WID * NB);
        __syncthreads();
#pragma unroll
        for (int hf = 0; hf < 2; ++hf) {
#pragma unroll
          for (int mp = 0; mp < 2; ++mp) {
            const int mt = hf * 2 + mp;
#pragma unroll
            for (int nt = 0; nt < 2; ++nt)
              *(f32x4*)&Pw[(nt * 16 + lr) * PSTR + mp * 16 + lk * 4] = acc[mt][nt];
          }
          __syncthreads();
          f32x2 s = {0.f, 0.f};
#pragma unroll
          for (int ww = 0; ww < 8; ++ww)
            s += *(const f32x2*)&P[ww * PWSZ + lcol * PSTR + r2];
          s += bias[hf];
          const int row = m0 + hf * 32 + r2;
          op[(size_t)(row + 0) * NB + n0 + lcol] = sigm(s[0]);  // cached; flushed at kernel end
          op[(size_t)(row + 1) * NB + n0 + lcol] = sigm(s[1]);
          if (hf == 0) __syncthreads();
        }
      }
      arrive(bar + 2);
    }

  } else {
    // ================= x role (works one phase ahead: writes x_{t+2}) =================
    const int xi = wg - 192;
    const int i0 = (xi >> 3) * 64;
    const int b0 = (xi & 7) * 32;
    const int c = tid & 31, rb = tid >> 5;
    for (int t = 0; t <= T_STEPS; ++t) {
      if (t <= T_STEPS - 3) {
        unsigned short* zx = zT + (size_t)((t + 2) & 3) * ZSZ;
        const float* xp = xs + (size_t)(t + 2) * (INP * NB) + (size_t)(i0 + rb * 4) * NB + b0 + c;
        ushort4v o;
#pragma unroll
        for (int j = 0; j < 4; ++j) o[j] = f2bf(xp[(size_t)j * NB]);
        // anti-dep on buf (t+2)&3: h readers of phase t-2 done (1 phase slack)
        if (t >= 2) {
          if (tid == 0) poll1(bar + 0, 16u * (unsigned)(t - 1));
        }
        __syncthreads();
        zst8(zx + (size_t)(b0 + c) * KZ + HID + i0 + rb * 4, o);
      }
      arrive(bar + 1);
    }
  }
}

// ---------------- host launch ----------------
extern "C" void kernel_launch(void* const* d_in, const int* in_sizes, int n_in,
                              void* d_out, int out_size, void* d_ws, size_t ws_size,
                              hipStream_t stream) {
  (void)in_sizes; (void)n_in; (void)out_size; (void)ws_size;
  const float* xs  = (const float*)d_in[0];
  const float* W_h = (const float*)d_in[1];
  const float* b_h = (const float*)d_in[2];
  const float* W_y = (const float*)d_in[3];
  const float* b_y = (const float*)d_in[4];
  const float* h0  = (const float*)d_in[5];
  float* out = (float*)d_out;

  // ws layout: zT bf16 [4][256][1536] ring | bars (512 u32)
  unsigned short* zT = (unsigned short*)d_ws;
  unsigned* bars = (unsigned*)(zT + 4 * (size_t)ZSZ);

  elman_setup<<<dim3(NB), dim3(256), 0, stream>>>(h0, xs, zT, bars);

  void* args[8];
  args[0] = (void*)&xs;  args[1] = (void*)&W_h; args[2] = (void*)&b_h;
  args[3] = (void*)&W_y; args[4] = (void*)&b_y; args[5] = (void*)&zT;
  args[6] = (void*)&out; args[7] = (void*)&bars;
  hipLaunchCooperativeKernel((void*)elman_seq, dim3(256), dim3(512), args, 0u, stream);
}

// Round 7
// 3068.334 us; speedup vs baseline: 1.4405x; 1.4405x over previous
//
#include <hip/hip_runtime.h>
#include <hip/hip_bf16.h>

#define T_STEPS 512
#define INP     512
#define NB      256
#define HID     1024
#define WID     512
#define KZ      1536   // HID + INP
#define ZSZ     (NB * KZ)

typedef short          bf16x8   __attribute__((ext_vector_type(8)));
typedef float          f32x4    __attribute__((ext_vector_type(4)));
typedef float          f32x2    __attribute__((ext_vector_type(2)));
typedef unsigned short ushort8  __attribute__((ext_vector_type(8)));
typedef unsigned short ushort2v __attribute__((ext_vector_type(2)));
typedef unsigned short ushort4v __attribute__((ext_vector_type(4)));
typedef unsigned long long u64;

__device__ __forceinline__ unsigned short f2bf(float x) {
  __hip_bfloat16 h = __float2bfloat16(x);
  return __builtin_bit_cast(unsigned short, h);
}
__device__ __forceinline__ float sigm(float x) { return 1.0f / (1.0f + __expf(-x)); }

// ---- coherence-point (LLC) resident accesses for the z ring buffer ----
// sc0|sc1 ops bypass the non-coherent L1/L2 and read/write the LLC directly
// (round-4 proven; no cache maintenance needed). Loads are batch-issued via
// inline asm so the whole fragment set costs ONE LLC round trip, not 24.
#define ZLOAD(dst, p) \
  asm volatile("global_load_dwordx4 %0, %1, off sc0 sc1" : "=v"(dst) : "v"(p))
#define ZWAIT() do { \
  asm volatile("s_waitcnt vmcnt(0)" ::: "memory"); \
  __builtin_amdgcn_sched_barrier(0); \
} while (0)

__device__ __forceinline__ void zst4(unsigned short* p, ushort2v v) {
  __hip_atomic_store((unsigned*)p, __builtin_bit_cast(unsigned, v),
                     __ATOMIC_RELAXED, __HIP_MEMORY_SCOPE_AGENT);
}
__device__ __forceinline__ void zst8(unsigned short* p, ushort4v v) {
  __hip_atomic_store((u64*)p, __builtin_bit_cast(u64, v),
                     __ATOMIC_RELAXED, __HIP_MEMORY_SCOPE_AGENT);
}

// ---- per-role monotonic tickets (agent scope, LLC — proven mechanism) ----
// bars layout per slice (64-word line): [0]=h_arr [1]=x_arr [2]=y_arr
__device__ __forceinline__ void poll1(unsigned* p, unsigned tgt) {
  while (__hip_atomic_load(p, __ATOMIC_RELAXED, __HIP_MEMORY_SCOPE_AGENT) < tgt)
    __builtin_amdgcn_s_sleep(1);
}
__device__ __forceinline__ void poll2(u64* p, unsigned lo, unsigned hi) {
  for (;;) {
    const u64 v = __hip_atomic_load(p, __ATOMIC_RELAXED, __HIP_MEMORY_SCOPE_AGENT);
    if ((unsigned)v >= lo && (unsigned)(v >> 32) >= hi) return;
    __builtin_amdgcn_s_sleep(1);
  }
}
// All my stores visible at LLC, then bump my role counter once per WG.
__device__ __forceinline__ void arrive(unsigned* ctr) {
  asm volatile("s_waitcnt vmcnt(0)" ::: "memory");
  __syncthreads();
  if (threadIdx.x == 0)
    __hip_atomic_fetch_add(ctr, 1u, __ATOMIC_RELAXED, __HIP_MEMORY_SCOPE_AGENT);
}

// ---------------- setup: z ring init (z_0 full, x_1 part), zero tickets ----------------
__global__ void elman_setup(const float* __restrict__ h0, const float* __restrict__ xs,
                            unsigned short* __restrict__ zT, unsigned* __restrict__ bars) {
  const int b = blockIdx.x;   // batch column 0..255
  if (b == 0) {
    for (int j = threadIdx.x; j < 512; j += blockDim.x) bars[j] = 0u;
  }
  for (int k = threadIdx.x; k < KZ; k += blockDim.x) {   // buf0 = z_0
    const float v = (k < HID) ? h0[k] : xs[(size_t)(k - HID) * NB + b];
    zT[(size_t)b * KZ + k] = f2bf(v);
  }
  for (int i = threadIdx.x; i < INP; i += blockDim.x)    // buf1 x-part = x_1
    zT[(size_t)ZSZ + (size_t)b * KZ + HID + i] = f2bf(xs[(size_t)(INP + i) * NB + b]);
}

// LDS partial-sum buffer: 8 waves x [32 cols][stride 36 words]
#define PSTR 36
#define PWSZ (32 * PSTR)

// ---------------- persistent sequential kernel ----------------
// 256 WGs x 512 threads. slice = wg & 7 (32 WGs: 16 h + 8 y + 8 x), 4-deep z ring.
// Phase t:  h: z_{t+1}h <- sigm(Wh @ z_t)          needs h_arr>=16t, x_arr>=8(t-1)
//           y: out[t-1] <- sigm(Wy @ z_t.h)        needs h_arr>=16t        (t>=1)
//           x: z_{t+2}.x <- xs[t+2]                needs h_arr>=16(t-1)    (t<=T-3)
// Anti-dep for h stores into buf (t+1)&3: y_arr >= 8(t-2) (checked after MFMA).
__global__ void __launch_bounds__(512, 2) elman_seq(
    const float* __restrict__ xs,
    const float* __restrict__ Wh, const float* __restrict__ bh,
    const float* __restrict__ Wy, const float* __restrict__ by,
    unsigned short* __restrict__ zT, float* __restrict__ out,
    unsigned* __restrict__ bars) {
  __shared__ float P[8 * PWSZ];
  const int wg = blockIdx.x, tid = threadIdx.x;
  const int w = tid >> 6, lane = tid & 63;
  const int lr = lane & 15, lk = lane >> 4;
  unsigned* bar = bars + (wg & 7) * 64;   // [0]=h_arr [1]=x_arr [2]=y_arr

  if (wg < 128) {
    // ================= h role =================
    const int m0 = (wg >> 3) * 64;
    const int n0 = (wg & 7) * 32;
    const int kw = w * 192;
    bf16x8 A[4][6];                         // resident W_h fragments: 96 VGPRs
#pragma unroll
    for (int mt = 0; mt < 4; ++mt)
#pragma unroll
      for (int kc = 0; kc < 6; ++kc) {
        const float* wp = Wh + (size_t)(m0 + mt * 16 + lr) * KZ + kw + kc * 32 + lk * 8;
        const f32x4 f0 = *(const f32x4*)wp;
        const f32x4 f1 = *(const f32x4*)(wp + 4);
        ushort8 a;
#pragma unroll
        for (int e = 0; e < 4; ++e) { a[e] = f2bf(f0[e]); a[4 + e] = f2bf(f1[e]); }
        A[mt][kc] = __builtin_bit_cast(bf16x8, a);
      }
    const int lcol = tid >> 4;
    const int r2 = (tid & 15) * 2;
    f32x2 bias[2];
#pragma unroll
    for (int hf = 0; hf < 2; ++hf) bias[hf] = *(const f32x2*)&bh[m0 + hf * 32 + r2];
    float* Pw = P + w * PWSZ;

    for (int t = 0; t <= T_STEPS; ++t) {
      if (t < T_STEPS) {
        const unsigned short* zc = zT + (size_t)(t & 3) * ZSZ;
        unsigned short* zn = zT + (size_t)((t + 1) & 3) * ZSZ;
        if (t >= 1) {
          if (tid == 0) poll2((u64*)bar, 16u * (unsigned)t,
                              (t >= 2) ? 8u * (unsigned)(t - 1) : 0u);
          __syncthreads();
        }
        const unsigned short* zb = zc + (size_t)(n0 + lr) * KZ + kw + lk * 8;
        // batch-issue ALL 12 fragment loads -> ONE LLC round trip
        bf16x8 bfr[6][2];
#pragma unroll
        for (int kc = 0; kc < 6; ++kc)
#pragma unroll
          for (int nt = 0; nt < 2; ++nt)
            ZLOAD(bfr[kc][nt], zb + nt * (16 * KZ) + kc * 32);
        ZWAIT();
        f32x4 acc[4][2];
#pragma unroll
        for (int mt = 0; mt < 4; ++mt)
#pragma unroll
          for (int nt = 0; nt < 2; ++nt) acc[mt][nt] = (f32x4){0.f, 0.f, 0.f, 0.f};
#pragma unroll
        for (int kc = 0; kc < 6; ++kc)
#pragma unroll
          for (int nt = 0; nt < 2; ++nt)
#pragma unroll
            for (int mt = 0; mt < 4; ++mt)
              acc[mt][nt] = __builtin_amdgcn_mfma_f32_16x16x32_bf16(A[mt][kc], bfr[kc][nt], acc[mt][nt], 0, 0, 0);
        // anti-dep on buf (t+1)&3: y readers of phase t-3 done (2 phases slack)
        if (t >= 3 && tid == 0) poll1(bar + 2, 8u * (unsigned)(t - 2));
        __syncthreads();
        // two-pass cross-wave K reduction through LDS
#pragma unroll
        for (int hf = 0; hf < 2; ++hf) {
#pragma unroll
          for (int mp = 0; mp < 2; ++mp) {
            const int mt = hf * 2 + mp;
#pragma unroll
            for (int nt = 0; nt < 2; ++nt)
              *(f32x4*)&Pw[(nt * 16 + lr) * PSTR + mp * 16 + lk * 4] = acc[mt][nt];
          }
          __syncthreads();
          f32x2 s = {0.f, 0.f};
#pragma unroll
          for (int ww = 0; ww < 8; ++ww)
            s += *(const f32x2*)&P[ww * PWSZ + lcol * PSTR + r2];
          s += bias[hf];
          ushort2v o2;
          o2[0] = f2bf(sigm(s[0]));
          o2[1] = f2bf(sigm(s[1]));
          zst4(zn + (size_t)(n0 + lcol) * KZ + m0 + hf * 32 + r2, o2);
          if (hf == 0) __syncthreads();
        }
      }
      arrive(bar + 0);
    }

  } else if (wg < 192) {
    // ================= y role =================
    const int idx = wg - 128;
    const int m0 = (idx >> 3) * 64;
    const int n0 = (idx & 7) * 32;
    const int kw = w * 128;
    bf16x8 A[4][4];                         // resident W_y fragments: 64 VGPRs
#pragma unroll
    for (int mt = 0; mt < 4; ++mt)
#pragma unroll
      for (int kc = 0; kc < 4; ++kc) {
        const float* wp = Wy + (size_t)(m0 + mt * 16 + lr) * HID + kw + kc * 32 + lk * 8;
        const f32x4 f0 = *(const f32x4*)wp;
        const f32x4 f1 = *(const f32x4*)(wp + 4);
        ushort8 a;
#pragma unroll
        for (int e = 0; e < 4; ++e) { a[e] = f2bf(f0[e]); a[4 + e] = f2bf(f1[e]); }
        A[mt][kc] = __builtin_bit_cast(bf16x8, a);
      }
    const int lcol = tid & 31;
    const int r2 = (tid >> 5) * 2;
    f32x2 bias[2];
#pragma unroll
    for (int hf = 0; hf < 2; ++hf) bias[hf] = *(const f32x2*)&by[m0 + hf * 32 + r2];
    float* Pw = P + w * PWSZ;

    for (int t = 0; t <= T_STEPS; ++t) {
      if (t >= 1) {
        const unsigned short* zc = zT + (size_t)(t & 3) * ZSZ;
        if (tid == 0) poll1(bar + 0, 16u * (unsigned)t);
        __syncthreads();
        const unsigned short* zb = zc + (size_t)(n0 + lr) * KZ + kw + lk * 8;
        bf16x8 bfr[4][2];
#pragma unroll
        for (int kc = 0; kc < 4; ++kc)
#pragma unroll
          for (int nt = 0; nt < 2; ++nt)
            ZLOAD(bfr[kc][nt], zb + nt * (16 * KZ) + kc * 32);
        ZWAIT();
        f32x4 acc[4][2];
#pragma unroll
        for (int mt = 0; mt < 4; ++mt)
#pragma unroll
          for (int nt = 0; nt < 2; ++nt) acc[mt][nt] = (f32x4){0.f, 0.f, 0.f, 0.f};
#pragma unroll
        for (int kc = 0; kc < 4; ++kc)
#pragma unroll
          for (int nt = 0; nt < 2; ++nt)
#pragma unroll
            for (int mt = 0; mt < 4; ++mt)
              acc[mt][nt] = __builtin_amdgcn_mfma_f32_16x16x32_bf16(A[mt][kc], bfr[kc][nt], acc[mt][nt], 0, 0, 0);
        float* op = out + (size_t)(t - 1) * (WID * NB);
        __syncthreads();
#pragma unroll
        for (int hf = 0; hf < 2; ++hf) {
#pragma unroll
          for (int mp = 0; mp < 2; ++mp) {
            const int mt = hf * 2 + mp;
#pragma unroll
            for (int nt = 0; nt < 2; ++nt)
              *(f32x4*)&Pw[(nt * 16 + lr) * PSTR + mp * 16 + lk * 4] = acc[mt][nt];
          }
          __syncthreads();
          f32x2 s = {0.f, 0.f};
#pragma unroll
          for (int ww = 0; ww < 8; ++ww)
            s += *(const f32x2*)&P[ww * PWSZ + lcol * PSTR + r2];
          s += bias[hf];
          const int row = m0 + hf * 32 + r2;
          op[(size_t)(row + 0) * NB + n0 + lcol] = sigm(s[0]);  // cached; flushed at kernel end
          op[(size_t)(row + 1) * NB + n0 + lcol] = sigm(s[1]);
          if (hf == 0) __syncthreads();
        }
      }
      arrive(bar + 2);
    }

  } else {
    // ================= x role (works one phase ahead: writes x_{t+2}) =================
    const int xi = wg - 192;
    const int i0 = (xi >> 3) * 64;
    const int b0 = (xi & 7) * 32;
    const int c = tid & 31, rb = tid >> 5;
    for (int t = 0; t <= T_STEPS; ++t) {
      if (t <= T_STEPS - 3) {
        unsigned short* zx = zT + (size_t)((t + 2) & 3) * ZSZ;
        const float* xp = xs + (size_t)(t + 2) * (INP * NB) + (size_t)(i0 + rb * 4) * NB + b0 + c;
        ushort4v o;
#pragma unroll
        for (int j = 0; j < 4; ++j) o[j] = f2bf(xp[(size_t)j * NB]);
        // anti-dep on buf (t+2)&3: h readers of phase t-2 done (1 phase slack)
        if (t >= 2) {
          if (tid == 0) poll1(bar + 0, 16u * (unsigned)(t - 1));
        }
        __syncthreads();
        zst8(zx + (size_t)(b0 + c) * KZ + HID + i0 + rb * 4, o);
      }
      arrive(bar + 1);
    }
  }
}

// ---------------- host launch ----------------
extern "C" void kernel_launch(void* const* d_in, const int* in_sizes, int n_in,
                              void* d_out, int out_size, void* d_ws, size_t ws_size,
                              hipStream_t stream) {
  (void)in_sizes; (void)n_in; (void)out_size; (void)ws_size;
  const float* xs  = (const float*)d_in[0];
  const float* W_h = (const float*)d_in[1];
  const float* b_h = (const float*)d_in[2];
  const float* W_y = (const float*)d_in[3];
  const float* b_y = (const float*)d_in[4];
  const float* h0  = (const float*)d_in[5];
  float* out = (float*)d_out;

  // ws layout: zT bf16 [4][256][1536] ring | bars (512 u32)
  unsigned short* zT = (unsigned short*)d_ws;
  unsigned* bars = (unsigned*)(zT + 4 * (size_t)ZSZ);

  elman_setup<<<dim3(NB), dim3(256), 0, stream>>>(h0, xs, zT, bars);

  void* args[8];
  args[0] = (void*)&xs;  args[1] = (void*)&W_h; args[2] = (void*)&b_h;
  args[3] = (void*)&W_y; args[4] = (void*)&b_y; args[5] = (void*)&zT;
  args[6] = (void*)&out; args[7] = (void*)&bars;
  hipLaunchCooperativeKernel((void*)elman_seq, dim3(256), dim3(512), args, 0u, stream);
}

// Round 8
// 2725.492 us; speedup vs baseline: 1.6217x; 1.1258x over previous
//
#include <hip/hip_runtime.h>
#include <hip/hip_bf16.h>

#define T_STEPS 512
#define INP     512
#define NB      256
#define HID     1024
#define WID     512
#define KZ      1536   // HID + INP
#define ZSZ     (NB * KZ)

typedef short          bf16x8   __attribute__((ext_vector_type(8)));
typedef float          f32x4    __attribute__((ext_vector_type(4)));
typedef float          f32x2    __attribute__((ext_vector_type(2)));
typedef unsigned short ushort8  __attribute__((ext_vector_type(8)));
typedef unsigned short ushort2v __attribute__((ext_vector_type(2)));
typedef unsigned short ushort4v __attribute__((ext_vector_type(4)));
typedef unsigned       uint4v   __attribute__((ext_vector_type(4)));
typedef unsigned long long u64;

__device__ __forceinline__ unsigned short f2bf(float x) {
  __hip_bfloat16 h = __float2bfloat16(x);
  return __builtin_bit_cast(unsigned short, h);
}
__device__ __forceinline__ float sigm(float x) { return 1.0f / (1.0f + __expf(-x)); }

// ---- z ring access, two coherence modes ----
// FAST (slice verified on ONE XCD): producers plain-store (commit to the XCD's
// coherent L2); consumers load sc0-only (bypass stale L1, HIT the shared L2 -
// the 24x slice re-read becomes L2-cached broadcast).
// SLOW (fallback): sc0|sc1 LLC-resident ops - byte-identical to round 7 (proven).
// Tickets are ALWAYS agent-scope LLC (round 5's L2-barrier hang is not reintroduced).
#define ZLOAD_FAST(dst, p) \
  asm volatile("global_load_dwordx4 %0, %1, off sc0" : "=v"(dst) : "v"(p))
#define ZLOAD_SLOW(dst, p) \
  asm volatile("global_load_dwordx4 %0, %1, off sc0 sc1" : "=v"(dst) : "v"(p))
#define ZWAIT() do { \
  asm volatile("s_waitcnt vmcnt(0)" ::: "memory"); \
  __builtin_amdgcn_sched_barrier(0); \
} while (0)

template <bool FAST>
__device__ __forceinline__ void zst4(unsigned short* p, ushort2v v) {
  if constexpr (FAST) *(unsigned*)p = __builtin_bit_cast(unsigned, v);
  else __hip_atomic_store((unsigned*)p, __builtin_bit_cast(unsigned, v),
                          __ATOMIC_RELAXED, __HIP_MEMORY_SCOPE_AGENT);
}
template <bool FAST>
__device__ __forceinline__ void zst8(unsigned short* p, ushort4v v) {
  if constexpr (FAST) *(u64*)p = __builtin_bit_cast(u64, v);
  else __hip_atomic_store((u64*)p, __builtin_bit_cast(u64, v),
                          __ATOMIC_RELAXED, __HIP_MEMORY_SCOPE_AGENT);
}

// ---- per-role monotonic tickets (agent scope, LLC - proven rounds 4/6/7) ----
// bars layout per slice (64-word line): [0]=h_arr [1]=x_arr [2]=y_arr
__device__ __forceinline__ void poll1(unsigned* p, unsigned tgt) {
  while (__hip_atomic_load(p, __ATOMIC_RELAXED, __HIP_MEMORY_SCOPE_AGENT) < tgt)
    __builtin_amdgcn_s_sleep(1);
}
// Merged h-poll: one 16B LLC read covers all three conditions (1 RT, not 2).
__device__ __forceinline__ void pollh(unsigned* bar, unsigned ht, unsigned xt, unsigned yt) {
  uint4v v;
  for (;;) {
    asm volatile("global_load_dwordx4 %0, %1, off sc0 sc1\n\ts_waitcnt vmcnt(0)"
                 : "=v"(v) : "v"(bar) : "memory");
    if (v.x >= ht && v.y >= xt && v.z >= yt) return;
    __builtin_amdgcn_s_sleep(1);
  }
}
// All my stores committed (L2 in FAST, LLC in SLOW), then bump my role counter.
__device__ __forceinline__ void arrive(unsigned* ctr) {
  asm volatile("s_waitcnt vmcnt(0)" ::: "memory");
  __syncthreads();
  if (threadIdx.x == 0)
    __hip_atomic_fetch_add(ctr, 1u, __ATOMIC_RELAXED, __HIP_MEMORY_SCOPE_AGENT);
}

// ---------------- setup: z ring init (z_0 full, x_1 part), zero tickets ----------------
__global__ void elman_setup(const float* __restrict__ h0, const float* __restrict__ xs,
                            unsigned short* __restrict__ zT, unsigned* __restrict__ bars) {
  const int b = blockIdx.x;   // batch column 0..255
  if (b == 0) {
    for (int j = threadIdx.x; j < 1024; j += blockDim.x) bars[j] = 0u;
  }
  for (int k = threadIdx.x; k < KZ; k += blockDim.x) {   // buf0 = z_0
    const float v = (k < HID) ? h0[k] : xs[(size_t)(k - HID) * NB + b];
    zT[(size_t)b * KZ + k] = f2bf(v);
  }
  for (int i = threadIdx.x; i < INP; i += blockDim.x)    // buf1 x-part = x_1
    zT[(size_t)ZSZ + (size_t)b * KZ + HID + i] = f2bf(xs[(size_t)(INP + i) * NB + b]);
}

// LDS partial-sum buffer: 8 waves x [32 cols][stride 36 words]
#define PSTR 36
#define PWSZ (32 * PSTR)

// ---------------- phase loop (templated on data-coherence mode) ----------------
// 256 WGs x 512 threads. slice = wg & 7 (32 WGs: 16 h + 8 y + 8 x), 4-deep z ring.
// Phase t:  h: z_{t+1}.h <- sigm(Wh @ z_t)   needs h>=16t, x>=8(t-1), y>=8(t-2)
//           y: out[t-1] <- sigm(Wy @ z_t.h)  needs h>=16t                (t>=1)
//           x: z_{t+2}.x <- xs[t+2]          needs h>=16(t-1)            (t<=T-3)
template <bool FAST>
__device__ __forceinline__ void run_phases(
    const float* __restrict__ xs,
    const float* __restrict__ Wh, const float* __restrict__ bh,
    const float* __restrict__ Wy, const float* __restrict__ by,
    unsigned short* __restrict__ zT, float* __restrict__ out,
    unsigned* bar, float* P, int wg, int tid) {
  const int w = tid >> 6, lane = tid & 63;
  const int lr = lane & 15, lk = lane >> 4;

  if (wg < 128) {
    // ================= h role =================
    const int m0 = (wg >> 3) * 64;
    const int n0 = (wg & 7) * 32;
    const int kw = w * 192;
    bf16x8 A[4][6];                         // resident W_h fragments: 96 VGPRs
#pragma unroll
    for (int mt = 0; mt < 4; ++mt)
#pragma unroll
      for (int kc = 0; kc < 6; ++kc) {
        const float* wp = Wh + (size_t)(m0 + mt * 16 + lr) * KZ + kw + kc * 32 + lk * 8;
        const f32x4 f0 = *(const f32x4*)wp;
        const f32x4 f1 = *(const f32x4*)(wp + 4);
        ushort8 a;
#pragma unroll
        for (int e = 0; e < 4; ++e) { a[e] = f2bf(f0[e]); a[4 + e] = f2bf(f1[e]); }
        A[mt][kc] = __builtin_bit_cast(bf16x8, a);
      }
    const int lcol = tid >> 4;
    const int r2 = (tid & 15) * 2;
    f32x2 bias[2];
#pragma unroll
    for (int hf = 0; hf < 2; ++hf) bias[hf] = *(const f32x2*)&bh[m0 + hf * 32 + r2];
    float* Pw = P + w * PWSZ;

    for (int t = 0; t <= T_STEPS; ++t) {
      if (t < T_STEPS) {
        const unsigned short* zc = zT + (size_t)(t & 3) * ZSZ;
        unsigned short* zn = zT + (size_t)((t + 1) & 3) * ZSZ;
        if (t >= 1) {
          // one LLC RT checks producer dep (h,x) AND ring anti-dep (y)
          if (tid == 0) pollh(bar, 16u * (unsigned)t, 8u * (unsigned)(t - 1),
                              (t >= 2) ? 8u * (unsigned)(t - 2) : 0u);
          __syncthreads();
        }
        const unsigned short* zb = zc + (size_t)(n0 + lr) * KZ + kw + lk * 8;
        bf16x8 bfr[6][2];
#pragma unroll
        for (int kc = 0; kc < 6; ++kc)
#pragma unroll
          for (int nt = 0; nt < 2; ++nt) {
            if constexpr (FAST) ZLOAD_FAST(bfr[kc][nt], zb + nt * (16 * KZ) + kc * 32);
            else                ZLOAD_SLOW(bfr[kc][nt], zb + nt * (16 * KZ) + kc * 32);
          }
        ZWAIT();
        f32x4 acc[4][2];
#pragma unroll
        for (int mt = 0; mt < 4; ++mt)
#pragma unroll
          for (int nt = 0; nt < 2; ++nt) acc[mt][nt] = (f32x4){0.f, 0.f, 0.f, 0.f};
#pragma unroll
        for (int kc = 0; kc < 6; ++kc)
#pragma unroll
          for (int nt = 0; nt < 2; ++nt)
#pragma unroll
            for (int mt = 0; mt < 4; ++mt)
              acc[mt][nt] = __builtin_amdgcn_mfma_f32_16x16x32_bf16(A[mt][kc], bfr[kc][nt], acc[mt][nt], 0, 0, 0);
        __syncthreads();   // previous phase's P reads complete before overwrite
        // two-pass cross-wave K reduction through LDS
#pragma unroll
        for (int hf = 0; hf < 2; ++hf) {
#pragma unroll
          for (int mp = 0; mp < 2; ++mp) {
            const int mt = hf * 2 + mp;
#pragma unroll
            for (int nt = 0; nt < 2; ++nt)
              *(f32x4*)&Pw[(nt * 16 + lr) * PSTR + mp * 16 + lk * 4] = acc[mt][nt];
          }
          __syncthreads();
          f32x2 s = {0.f, 0.f};
#pragma unroll
          for (int ww = 0; ww < 8; ++ww)
            s += *(const f32x2*)&P[ww * PWSZ + lcol * PSTR + r2];
          s += bias[hf];
          ushort2v o2;
          o2[0] = f2bf(sigm(s[0]));
          o2[1] = f2bf(sigm(s[1]));
          zst4<FAST>(zn + (size_t)(n0 + lcol) * KZ + m0 + hf * 32 + r2, o2);
          if (hf == 0) __syncthreads();
        }
      }
      arrive(bar + 0);
    }

  } else if (wg < 192) {
    // ================= y role =================
    const int idx = wg - 128;
    const int m0 = (idx >> 3) * 64;
    const int n0 = (idx & 7) * 32;
    const int kw = w * 128;
    bf16x8 A[4][4];                         // resident W_y fragments: 64 VGPRs
#pragma unroll
    for (int mt = 0; mt < 4; ++mt)
#pragma unroll
      for (int kc = 0; kc < 4; ++kc) {
        const float* wp = Wy + (size_t)(m0 + mt * 16 + lr) * HID + kw + kc * 32 + lk * 8;
        const f32x4 f0 = *(const f32x4*)wp;
        const f32x4 f1 = *(const f32x4*)(wp + 4);
        ushort8 a;
#pragma unroll
        for (int e = 0; e < 4; ++e) { a[e] = f2bf(f0[e]); a[4 + e] = f2bf(f1[e]); }
        A[mt][kc] = __builtin_bit_cast(bf16x8, a);
      }
    const int lcol = tid & 31;
    const int r2 = (tid >> 5) * 2;
    f32x2 bias[2];
#pragma unroll
    for (int hf = 0; hf < 2; ++hf) bias[hf] = *(const f32x2*)&by[m0 + hf * 32 + r2];
    float* Pw = P + w * PWSZ;

    for (int t = 0; t <= T_STEPS; ++t) {
      if (t >= 1) {
        const unsigned short* zc = zT + (size_t)(t & 3) * ZSZ;
        if (tid == 0) poll1(bar + 0, 16u * (unsigned)t);
        __syncthreads();
        const unsigned short* zb = zc + (size_t)(n0 + lr) * KZ + kw + lk * 8;
        bf16x8 bfr[4][2];
#pragma unroll
        for (int kc = 0; kc < 4; ++kc)
#pragma unroll
          for (int nt = 0; nt < 2; ++nt) {
            if constexpr (FAST) ZLOAD_FAST(bfr[kc][nt], zb + nt * (16 * KZ) + kc * 32);
            else                ZLOAD_SLOW(bfr[kc][nt], zb + nt * (16 * KZ) + kc * 32);
          }
        ZWAIT();
        f32x4 acc[4][2];
#pragma unroll
        for (int mt = 0; mt < 4; ++mt)
#pragma unroll
          for (int nt = 0; nt < 2; ++nt) acc[mt][nt] = (f32x4){0.f, 0.f, 0.f, 0.f};
#pragma unroll
        for (int kc = 0; kc < 4; ++kc)
#pragma unroll
          for (int nt = 0; nt < 2; ++nt)
#pragma unroll
            for (int mt = 0; mt < 4; ++mt)
              acc[mt][nt] = __builtin_amdgcn_mfma_f32_16x16x32_bf16(A[mt][kc], bfr[kc][nt], acc[mt][nt], 0, 0, 0);
        float* op = out + (size_t)(t - 1) * (WID * NB);
        __syncthreads();
#pragma unroll
        for (int hf = 0; hf < 2; ++hf) {
#pragma unroll
          for (int mp = 0; mp < 2; ++mp) {
            const int mt = hf * 2 + mp;
#pragma unroll
            for (int nt = 0; nt < 2; ++nt)
              *(f32x4*)&Pw[(nt * 16 + lr) * PSTR + mp * 16 + lk * 4] = acc[mt][nt];
          }
          __syncthreads();
          f32x2 s = {0.f, 0.f};
#pragma unroll
          for (int ww = 0; ww < 8; ++ww)
            s += *(const f32x2*)&P[ww * PWSZ + lcol * PSTR + r2];
          s += bias[hf];
          const int row = m0 + hf * 32 + r2;
          op[(size_t)(row + 0) * NB + n0 + lcol] = sigm(s[0]);  // cached; flushed at kernel end
          op[(size_t)(row + 1) * NB + n0 + lcol] = sigm(s[1]);
          if (hf == 0) __syncthreads();
        }
      }
      arrive(bar + 2);
    }

  } else {
    // ================= x role (one phase ahead: writes x_{t+2}) =================
    const int xi = wg - 192;
    const int i0 = (xi >> 3) * 64;
    const int b0 = (xi & 7) * 32;
    const int c = tid & 31, rb = tid >> 5;
    for (int t = 0; t <= T_STEPS; ++t) {
      if (t <= T_STEPS - 3) {
        unsigned short* zx = zT + (size_t)((t + 2) & 3) * ZSZ;
        const float* xp = xs + (size_t)(t + 2) * (INP * NB) + (size_t)(i0 + rb * 4) * NB + b0 + c;
        ushort4v o;
#pragma unroll
        for (int j = 0; j < 4; ++j) o[j] = f2bf(xp[(size_t)j * NB]);
        // anti-dep on buf (t+2)&3: h readers of phase t-2 done (1 phase slack)
        if (t >= 2) {
          if (tid == 0) poll1(bar + 0, 16u * (unsigned)(t - 1));
        }
        __syncthreads();
        zst8<FAST>(zx + (size_t)(b0 + c) * KZ + HID + i0 + rb * 4, o);
      }
      arrive(bar + 1);
    }
  }
}

// ---------------- persistent sequential kernel ----------------
__global__ void __launch_bounds__(512, 2) elman_seq(
    const float* __restrict__ xs,
    const float* __restrict__ Wh, const float* __restrict__ bh,
    const float* __restrict__ Wy, const float* __restrict__ by,
    unsigned short* __restrict__ zT, float* __restrict__ out,
    unsigned* __restrict__ bars) {
  __shared__ float P[8 * PWSZ];
  __shared__ unsigned modeSh;
  const int wg = blockIdx.x, tid = threadIdx.x;
  unsigned* bar  = bars + (wg & 7) * 64;   // [0]=h_arr [1]=x_arr [2]=y_arr
  unsigned* xcds = bars + 512;             // [512..767]
  unsigned* hbar = bars + 768;             // one-shot handshake counter

  // one-shot handshake: does this slice sit on ONE XCD? (all ops agent-scope LLC)
  unsigned xcc;
  asm volatile("s_getreg_b32 %0, hwreg(HW_REG_XCC_ID)" : "=s"(xcc));
  if (tid == 0) {
    __hip_atomic_store(&xcds[wg], xcc + 1u, __ATOMIC_RELAXED, __HIP_MEMORY_SCOPE_AGENT);
    asm volatile("s_waitcnt vmcnt(0)" ::: "memory");
    __hip_atomic_fetch_add(hbar, 1u, __ATOMIC_RELAXED, __HIP_MEMORY_SCOPE_AGENT);
    while (__hip_atomic_load(hbar, __ATOMIC_RELAXED, __HIP_MEMORY_SCOPE_AGENT) < 256u)
      __builtin_amdgcn_s_sleep(1);
    const unsigned v0 = __hip_atomic_load(&xcds[wg & 7], __ATOMIC_RELAXED, __HIP_MEMORY_SCOPE_AGENT);
    unsigned m = 1u;
    for (int j = 1; j < 32; ++j)
      m &= (__hip_atomic_load(&xcds[(wg & 7) + 8 * j], __ATOMIC_RELAXED,
                              __HIP_MEMORY_SCOPE_AGENT) == v0) ? 1u : 0u;
    modeSh = m;
  }
  __syncthreads();

  if (modeSh)
    run_phases<true >(xs, Wh, bh, Wy, by, zT, out, bar, P, wg, tid);
  else
    run_phases<false>(xs, Wh, bh, Wy, by, zT, out, bar, P, wg, tid);
}

// ---------------- host launch ----------------
extern "C" void kernel_launch(void* const* d_in, const int* in_sizes, int n_in,
                              void* d_out, int out_size, void* d_ws, size_t ws_size,
                              hipStream_t stream) {
  (void)in_sizes; (void)n_in; (void)out_size; (void)ws_size;
  const float* xs  = (const float*)d_in[0];
  const float* W_h = (const float*)d_in[1];
  const float* b_h = (const float*)d_in[2];
  const float* W_y = (const float*)d_in[3];
  const float* b_y = (const float*)d_in[4];
  const float* h0  = (const float*)d_in[5];
  float* out = (float*)d_out;

  // ws layout: zT bf16 [4][256][1536] ring | bars/xcds/hbar (1024 u32)
  unsigned short* zT = (unsigned short*)d_ws;
  unsigned* bars = (unsigned*)(zT + 4 * (size_t)ZSZ);

  elman_setup<<<dim3(NB), dim3(256), 0, stream>>>(h0, xs, zT, bars);

  void* args[8];
  args[0] = (void*)&xs;  args[1] = (void*)&W_h; args[2] = (void*)&b_h;
  args[3] = (void*)&W_y; args[4] = (void*)&b_y; args[5] = (void*)&zT;
  args[6] = (void*)&out; args[7] = (void*)&bars;
  hipLaunchCooperativeKernel((void*)elman_seq, dim3(256), dim3(512), args, 0u, stream);
}